// Round 4
// baseline (112.121 us; speedup 1.0000x reference)
//
#include <hip/hip_runtime.h>
#include <math.h>

#define NQ 512
#define NC 8000
#define DNUM 6
#define NBINS 50
#define DCAT 20
#define DENC 26      // DNUM + DCAT
#define DOUT 10
#define CHUNK 1000
#define NCHUNK 8
#define SPLIT 4      // subchunks per chunk
#define SUBC 250     // CHUNK / SPLIT, candidates per block (1 per thread)
#define QT 4         // queries per block

// ---------- encode ----------
// G_f(v) = sum_j ceil((v - u_fj*delta_fj)/delta_fj). Each per-bin map is
// fp-monotone in v (sub, div-by-positive, ceil), so all 50 bin diffs for a
// feature share sign => sum_j |bin_j(x)-bin_j(c)| == |G_f(x)-G_f(c)| exactly
// (integer-valued floats, sums << 2^24). 320-dim L1 -> 26-dim L1.
__global__ void encode(const float* __restrict__ c_num, const float* __restrict__ c_cat,
                       const float* __restrict__ x_num, const float* __restrict__ x_cat,
                       const float* __restrict__ delta, const float* __restrict__ u,
                       float* __restrict__ cEnc, float* __restrict__ qEnc,
                       float* __restrict__ g_logits) {
    int i = blockIdx.x * 256 + threadIdx.x;
    const int nA = (NC + NQ) * DNUM;          // 51072
    const int nB = (NC + NQ) * DCAT;          // 170240
    if (i < nA) {
        int f = i % DNUM, p = i / DNUM;
        bool is_c = p < NC;
        int idx = is_c ? p : p - NC;
        float v = (is_c ? c_num : x_num)[idx * DNUM + f];
        float g = 0.f;
        for (int j = 0; j < NBINS; ++j) {
            // exact reference op order: scaled_u = u*delta; ceil((v - scaled_u)/delta)
            float dl = delta[f * NBINS + j];
            float sc = u[f * NBINS + j] * dl;
            g += ceilf((v - sc) / dl);
        }
        if (is_c) cEnc[f * NC + idx] = g;
        else      qEnc[f * NQ + idx] = g;
    } else if (i < nA + nB) {
        int i2 = i - nA;
        int k = i2 % DCAT, p = i2 / DCAT;
        bool is_c = p < NC;
        int idx = is_c ? p : p - NC;
        float v = (is_c ? c_cat : x_cat)[idx * DCAT + k];
        if (is_c) cEnc[(DNUM + k) * NC + idx] = v;
        else      qEnc[(DNUM + k) * NQ + idx] = v;
    } else {
        int i3 = i - nA - nB;
        if (i3 < NQ * DOUT) g_logits[i3] = 0.f;
    }
}

// ---------- main: block = (4-query tile, 250-candidate subchunk) ----------
// grid = (NCHUNK*SPLIT, NQ/QT) = (32, 128) = 4096 blocks, 256 threads.
// chunk-sub on blockIdx.x: linear_id % 8 is constant per bx -> all 128
// q-blocks of one candidate slice land on the same XCD's L2.
__global__ __launch_bounds__(256) void nca_main(
    const float* __restrict__ cEnc, const float* __restrict__ qEnc,
    const int* __restrict__ cy,
    float* __restrict__ g_logits, float* __restrict__ parts) {
    __shared__ float qs[DENC * QT];           // 104 floats
    __shared__ float lds_logits[QT * DOUT];   // 40
    __shared__ float wred[QT * 4];
    __shared__ float m_sh[QT];

    const int tid = threadIdx.x;
    const int chunk = blockIdx.x / SPLIT;
    const int sub = blockIdx.x % SPLIT;
    const int q0 = blockIdx.y * QT;

    if (tid < DENC * QT) {
        int d = tid >> 2, q = tid & 3;
        qs[tid] = qEnc[d * NQ + q0 + q];
    }
    if (tid < QT * DOUT) lds_logits[tid] = 0.f;
    __syncthreads();

    const bool active = (tid < SUBC);
    const int cl = chunk * CHUNK + sub * SUBC + (active ? tid : SUBC - 1);
    const float* cp = cEnc + cl;

    float acc[QT] = {0.f, 0.f, 0.f, 0.f};
#pragma unroll
    for (int d = 0; d < DENC; ++d) {
        float cv = cp[(size_t)d * NC];                     // coalesced dword
        float4 xq = *(const float4*)(qs + d * QT);         // LDS broadcast b128
        acc[0] += fabsf(cv - xq.x);
        acc[1] += fabsf(cv - xq.y);
        acc[2] += fabsf(cv - xq.z);
        acc[3] += fabsf(cv - xq.w);
    }

    // ---- logits partial: sum exp(-dist) per class ----
    if (active) {
        int y = cy[cl];
#pragma unroll
        for (int q = 0; q < QT; ++q)
            atomicAdd(&lds_logits[q * DOUT + y], __expf(-acc[q]));
    }

    const int lane = tid & 63, wave = tid >> 6;

    // ---- per-q subchunk min(dist) ----
#pragma unroll
    for (int q = 0; q < QT; ++q) {
        float v = active ? acc[q] : INFINITY;
#pragma unroll
        for (int m = 32; m >= 1; m >>= 1) v = fminf(v, __shfl_xor(v, m));
        if (lane == 0) wred[q * 4 + wave] = v;
    }
    __syncthreads();
    if (tid < QT) {
        float m = wred[tid * 4];
#pragma unroll
        for (int w = 1; w < 4; ++w) m = fminf(m, wred[tid * 4 + w]);
        m_sh[tid] = m;
    }
    __syncthreads();

    // ---- stable partial sum: s = sum exp(m - dist) ----
#pragma unroll
    for (int q = 0; q < QT; ++q) {
        float s = active ? __expf(m_sh[q] - acc[q]) : 0.f;
#pragma unroll
        for (int mm = 32; mm >= 1; mm >>= 1) s += __shfl_xor(s, mm);
        if (lane == 0) wred[q * 4 + wave] = s;
    }
    __syncthreads();
    if (tid < QT) {
        float s = 0.f;
#pragma unroll
        for (int w = 0; w < 4; ++w) s += wred[tid * 4 + w];
        // partial (m, s): sum_c exp(-d) over this subchunk = exp(-m) * s
        int qg = q0 + tid;
        float2 ms = make_float2(m_sh[tid], s);
        *(float2*)(parts + 2 * (((size_t)qg * NCHUNK + chunk) * SPLIT + sub)) = ms;
    }
    __syncthreads();
    if (tid < QT * DOUT)
        atomicAdd(&g_logits[q0 * DOUT + tid], lds_logits[tid]);
}

// ---------- finalize: combine subchunk lse partials, write output ----------
__global__ void finalize(const float* __restrict__ g_logits, const float* __restrict__ parts,
                         float* __restrict__ out) {
    int q = blockIdx.x * 256 + threadIdx.x;
    if (q >= NQ) return;
    float lse = 0.f;
    for (int ch = 0; ch < NCHUNK; ++ch) {
        const float* p = parts + 2 * (((size_t)q * NCHUNK + ch) * SPLIT);
        float M = INFINITY;
#pragma unroll
        for (int s = 0; s < SPLIT; ++s) M = fminf(M, p[2 * s]);
        float S = 0.f;
#pragma unroll
        for (int s = 0; s < SPLIT; ++s) S += __expf(M - p[2 * s]) * p[2 * s + 1];
        // lse_chunk = log(sum_c exp(-d)) = -M + log(S)
        lse += logf(S) - M;
    }
#pragma unroll
    for (int k = 0; k < DOUT; ++k)
        out[q * DOUT + k] = logf(g_logits[q * DOUT + k] + 1e-8f) - lse;
}

extern "C" void kernel_launch(void* const* d_in, const int* in_sizes, int n_in,
                              void* d_out, int out_size, void* d_ws, size_t ws_size,
                              hipStream_t stream) {
    const float* x_num = (const float*)d_in[0];
    const float* x_cat = (const float*)d_in[1];
    const float* c_num = (const float*)d_in[2];
    const float* c_cat = (const float*)d_in[3];
    const int*   c_y   = (const int*)d_in[4];
    const float* delta = (const float*)d_in[5];
    const float* u     = (const float*)d_in[6];

    float* ws = (float*)d_ws;
    float* cEnc = ws;                             // 26*8000 = 208,000 floats
    float* qEnc = cEnc + (size_t)DENC * NC;       // 26*512  = 13,312
    float* g_logits = qEnc + (size_t)DENC * NQ;   // 5,120
    float* parts = g_logits + NQ * DOUT;          // 512*8*4*2 = 32,768

    const int total = (NC + NQ) * (DNUM + DCAT) + NQ * DOUT;
    encode<<<(total + 255) / 256, 256, 0, stream>>>(
        c_num, c_cat, x_num, x_cat, delta, u, cEnc, qEnc, g_logits);
    nca_main<<<dim3(NCHUNK * SPLIT, NQ / QT), 256, 0, stream>>>(
        cEnc, qEnc, c_y, g_logits, parts);
    finalize<<<(NQ + 255) / 256, 256, 0, stream>>>(g_logits, parts, (float*)d_out);
}

// Round 5
// 111.855 us; speedup vs baseline: 1.0024x; 1.0024x over previous
//
#include <hip/hip_runtime.h>
#include <math.h>

#define NQ 512
#define NC 8000
#define DNUM 6
#define NBINS 50
#define DCAT 20
#define DENC 26      // DNUM + DCAT
#define QSTRIDE 32   // qEnc row stride (padded for aligned scalar loads)
#define DOUT 10
#define CHUNK 1000
#define NCHUNK 8
#define SPLIT 4      // subchunks per chunk
#define SUBC 250     // CHUNK / SPLIT, candidates per block (1 per thread)
#define QT 8         // queries per block

// ---------- encode ----------
// G_f(v) = sum_j ceil((v - u_fj*delta_fj)/delta_fj). Each per-bin map is
// fp-monotone in v (sub, div-by-positive, ceil), so all 50 bin diffs for a
// feature share sign => sum_j |bin_j(x)-bin_j(c)| == |G_f(x)-G_f(c)| exactly
// (integer-valued floats, sums << 2^24). 320-dim L1 -> 26-dim L1.
// cEnc is d-major [d][NC] (coalesced vector loads in main);
// qEnc is q-major [q][QSTRIDE] (wave-uniform contiguous -> scalar K$ loads).
__global__ void encode(const float* __restrict__ c_num, const float* __restrict__ c_cat,
                       const float* __restrict__ x_num, const float* __restrict__ x_cat,
                       const float* __restrict__ delta, const float* __restrict__ u,
                       float* __restrict__ cEnc, float* __restrict__ qEnc,
                       float* __restrict__ g_logits) {
    int i = blockIdx.x * 256 + threadIdx.x;
    const int nA = (NC + NQ) * DNUM;          // 51072
    const int nB = (NC + NQ) * DCAT;          // 170240
    if (i < nA) {
        int f = i % DNUM, p = i / DNUM;
        bool is_c = p < NC;
        int idx = is_c ? p : p - NC;
        float v = (is_c ? c_num : x_num)[idx * DNUM + f];
        float g = 0.f;
        for (int j = 0; j < NBINS; ++j) {
            // exact reference op order: scaled_u = u*delta; ceil((v - scaled_u)/delta)
            float dl = delta[f * NBINS + j];
            float sc = u[f * NBINS + j] * dl;
            g += ceilf((v - sc) / dl);
        }
        if (is_c) cEnc[f * NC + idx] = g;
        else      qEnc[idx * QSTRIDE + f] = g;
    } else if (i < nA + nB) {
        int i2 = i - nA;
        int k = i2 % DCAT, p = i2 / DCAT;
        bool is_c = p < NC;
        int idx = is_c ? p : p - NC;
        float v = (is_c ? c_cat : x_cat)[idx * DCAT + k];
        if (is_c) cEnc[(DNUM + k) * NC + idx] = v;
        else      qEnc[idx * QSTRIDE + DNUM + k] = v;
    } else {
        int i3 = i - nA - nB;
        if (i3 < NQ * DOUT) g_logits[i3] = 0.f;
    }
}

// ---------- main: block = (8-query tile, 250-candidate subchunk) ----------
// grid = (NCHUNK*SPLIT, NQ/QT) = (32, 64) = 2048 blocks = exactly 8/CU,
// one residency round at 32 waves/CU. Candidate dims live in VGPRs; query
// dims are wave-uniform scalar loads. No LDS in the hot loop.
__global__ __launch_bounds__(256, 8) void nca_main(
    const float* __restrict__ cEnc, const float* __restrict__ qEnc,
    const int* __restrict__ cy,
    float* __restrict__ g_logits, float* __restrict__ parts) {
    __shared__ float lds_logits[QT * DOUT];   // 80 floats
    __shared__ float wred[QT * 4];
    __shared__ float m_sh[QT];

    const int tid = threadIdx.x;
    const int chunk = blockIdx.x / SPLIT;
    const int sub = blockIdx.x % SPLIT;
    const int q0 = blockIdx.y * QT;

    if (tid < QT * DOUT) lds_logits[tid] = 0.f;
    __syncthreads();

    const bool active = (tid < SUBC);
    const int cl = chunk * CHUNK + sub * SUBC + (active ? tid : SUBC - 1);

    // one candidate per thread, 26 dims in VGPRs (coalesced loads, pipelined)
    float cv[DENC];
#pragma unroll
    for (int d = 0; d < DENC; ++d) cv[d] = cEnc[(size_t)d * NC + cl];

    float acc[QT];
#pragma unroll
    for (int q = 0; q < QT; ++q) {
        const float* qp = qEnc + (size_t)(q0 + q) * QSTRIDE;  // wave-uniform -> s_load
        float a = 0.f;
#pragma unroll
        for (int d = 0; d < DENC; ++d) a += fabsf(cv[d] - qp[d]);
        acc[q] = a;
    }

    // ---- logits partial: sum exp(-dist) per class ----
    if (active) {
        int y = cy[cl];
#pragma unroll
        for (int q = 0; q < QT; ++q)
            atomicAdd(&lds_logits[q * DOUT + y], __expf(-acc[q]));
    }

    const int lane = tid & 63, wave = tid >> 6;

    // ---- per-q subchunk min(dist) ----
#pragma unroll
    for (int q = 0; q < QT; ++q) {
        float v = active ? acc[q] : INFINITY;
#pragma unroll
        for (int m = 32; m >= 1; m >>= 1) v = fminf(v, __shfl_xor(v, m));
        if (lane == 0) wred[q * 4 + wave] = v;
    }
    __syncthreads();
    if (tid < QT) {
        float m = wred[tid * 4];
#pragma unroll
        for (int w = 1; w < 4; ++w) m = fminf(m, wred[tid * 4 + w]);
        m_sh[tid] = m;
    }
    __syncthreads();

    // ---- stable partial sum: s = sum exp(m - dist) ----
#pragma unroll
    for (int q = 0; q < QT; ++q) {
        float s = active ? __expf(m_sh[q] - acc[q]) : 0.f;
#pragma unroll
        for (int mm = 32; mm >= 1; mm >>= 1) s += __shfl_xor(s, mm);
        if (lane == 0) wred[q * 4 + wave] = s;
    }
    __syncthreads();
    if (tid < QT) {
        float s = 0.f;
#pragma unroll
        for (int w = 0; w < 4; ++w) s += wred[tid * 4 + w];
        // partial (m, s): sum_c exp(-d) over this subchunk = exp(-m) * s
        int qg = q0 + tid;
        float2 ms = make_float2(m_sh[tid], s);
        *(float2*)(parts + 2 * (((size_t)qg * NCHUNK + chunk) * SPLIT + sub)) = ms;
    }
    __syncthreads();
    if (tid < QT * DOUT)
        atomicAdd(&g_logits[q0 * DOUT + tid], lds_logits[tid]);
}

// ---------- finalize: combine subchunk lse partials, write output ----------
__global__ void finalize(const float* __restrict__ g_logits, const float* __restrict__ parts,
                         float* __restrict__ out) {
    int q = blockIdx.x * 256 + threadIdx.x;
    if (q >= NQ) return;
    float lse = 0.f;
    for (int ch = 0; ch < NCHUNK; ++ch) {
        const float* p = parts + 2 * (((size_t)q * NCHUNK + ch) * SPLIT);
        float M = INFINITY;
#pragma unroll
        for (int s = 0; s < SPLIT; ++s) M = fminf(M, p[2 * s]);
        float S = 0.f;
#pragma unroll
        for (int s = 0; s < SPLIT; ++s) S += __expf(M - p[2 * s]) * p[2 * s + 1];
        // lse_chunk = log(sum_c exp(-d)) = -M + log(S)
        lse += logf(S) - M;
    }
#pragma unroll
    for (int k = 0; k < DOUT; ++k)
        out[q * DOUT + k] = logf(g_logits[q * DOUT + k] + 1e-8f) - lse;
}

extern "C" void kernel_launch(void* const* d_in, const int* in_sizes, int n_in,
                              void* d_out, int out_size, void* d_ws, size_t ws_size,
                              hipStream_t stream) {
    const float* x_num = (const float*)d_in[0];
    const float* x_cat = (const float*)d_in[1];
    const float* c_num = (const float*)d_in[2];
    const float* c_cat = (const float*)d_in[3];
    const int*   c_y   = (const int*)d_in[4];
    const float* delta = (const float*)d_in[5];
    const float* u     = (const float*)d_in[6];

    float* ws = (float*)d_ws;
    float* cEnc = ws;                             // 26*8000 = 208,000 floats
    float* qEnc = cEnc + (size_t)DENC * NC;       // 512*32  = 16,384
    float* g_logits = qEnc + (size_t)NQ * QSTRIDE;// 5,120
    float* parts = g_logits + NQ * DOUT;          // 512*8*4*2 = 32,768

    const int total = (NC + NQ) * (DNUM + DCAT) + NQ * DOUT;
    encode<<<(total + 255) / 256, 256, 0, stream>>>(
        c_num, c_cat, x_num, x_cat, delta, u, cEnc, qEnc, g_logits);
    nca_main<<<dim3(NCHUNK * SPLIT, NQ / QT), 256, 0, stream>>>(
        cEnc, qEnc, c_y, g_logits, parts);
    finalize<<<(NQ + 255) / 256, 256, 0, stream>>>(g_logits, parts, (float*)d_out);
}

// Round 6
// 106.494 us; speedup vs baseline: 1.0528x; 1.0503x over previous
//
#include <hip/hip_runtime.h>
#include <math.h>

#define NQ 512
#define NC 8000
#define DNUM 6
#define NBINS 50
#define DCAT 20
#define DENC 26      // DNUM + DCAT
#define DOUT 10
#define CHUNK 1000
#define NCHUNK 8
#define QT 8         // queries per block
#define CPT 4        // candidates per thread (250 active threads * 4 = 1000)

// ---------- encode ----------
// G_f(v) = sum_j ceil((v - u_fj*delta_fj)/delta_fj). Each per-bin map is
// fp-monotone in v (sub, div-by-positive, ceil), so all 50 bin diffs for a
// feature share sign => sum_j |bin_j(x)-bin_j(c)| == |G_f(x)-G_f(c)| exactly
// (integer-valued floats, sums << 2^24). 320-dim L1 -> 26-dim L1.
// cEnc d-major [d][NC] (coalesced float4 loads); qEnc d-major [d][NQ]
// (8 contiguous floats per (d, q-tile) -> one s_load_dwordx8).
__global__ void encode(const float* __restrict__ c_num, const float* __restrict__ c_cat,
                       const float* __restrict__ x_num, const float* __restrict__ x_cat,
                       const float* __restrict__ delta, const float* __restrict__ u,
                       float* __restrict__ cEnc, float* __restrict__ qEnc,
                       float* __restrict__ g_logits) {
    int i = blockIdx.x * 256 + threadIdx.x;
    const int nA = (NC + NQ) * DNUM;          // 51072
    const int nB = (NC + NQ) * DCAT;          // 170240
    if (i < nA) {
        int f = i % DNUM, p = i / DNUM;
        bool is_c = p < NC;
        int idx = is_c ? p : p - NC;
        float v = (is_c ? c_num : x_num)[idx * DNUM + f];
        float g = 0.f;
        for (int j = 0; j < NBINS; ++j) {
            // exact reference op order: scaled_u = u*delta; ceil((v - scaled_u)/delta)
            float dl = delta[f * NBINS + j];
            float sc = u[f * NBINS + j] * dl;
            g += ceilf((v - sc) / dl);
        }
        if (is_c) cEnc[f * NC + idx] = g;
        else      qEnc[f * NQ + idx] = g;
    } else if (i < nA + nB) {
        int i2 = i - nA;
        int k = i2 % DCAT, p = i2 / DCAT;
        bool is_c = p < NC;
        int idx = is_c ? p : p - NC;
        float v = (is_c ? c_cat : x_cat)[idx * DCAT + k];
        if (is_c) cEnc[(DNUM + k) * NC + idx] = v;
        else      qEnc[(DNUM + k) * NQ + idx] = v;
    } else {
        int i3 = i - nA - nB;
        if (i3 < NQ * DOUT) g_logits[i3] = 0.f;
    }
}

// ---------- main: block = (8-query tile, one full 1000-candidate chunk) ----------
// grid (NCHUNK, NQ/QT) = (8, 64) = 512 blocks = 2/CU = 8 waves/CU.
// KEY: __launch_bounds__(256, 2) -> 256-VGPR cap. R3/R5's anomalously low
// VGPR_Count (32/20 vs >=34 live values) showed the allocator spilling acc /
// rematerializing candidate loads; declaring only 2 waves/EU (which matches
// the grid's true residency) lets ~50 live VGPRs stay in registers and the
// 26 independent d-iterations software-pipeline.
__global__ __launch_bounds__(256, 2) void nca_main(
    const float* __restrict__ cEnc, const float* __restrict__ qEnc,
    const int* __restrict__ cy,
    float* __restrict__ g_logits, float* __restrict__ parts) {
    __shared__ float lds_logits[QT * DOUT];   // 80 floats
    __shared__ float wred[QT * 4];
    __shared__ float m_sh[QT];

    const int tid = threadIdx.x;
    const int chunk = blockIdx.x;
    const int q0 = blockIdx.y * QT;

    if (tid < QT * DOUT) lds_logits[tid] = 0.f;
    __syncthreads();

    const bool active = (tid < CHUNK / CPT);               // 250
    const int cl = chunk * CHUNK + (active ? CPT * tid : CHUNK - CPT);
    const float* cp = cEnc + cl;

    float4 acc[QT];
#pragma unroll
    for (int q = 0; q < QT; ++q) acc[q] = make_float4(0.f, 0.f, 0.f, 0.f);

#pragma unroll
    for (int d = 0; d < DENC; ++d) {
        float4 cv = *(const float4*)(cp + (size_t)d * NC);     // coalesced 16B
        const float* qrow = qEnc + (size_t)d * NQ + q0;        // uniform -> s_load_dwordx8
#pragma unroll
        for (int q = 0; q < QT; ++q) {
            float xq = qrow[q];
            acc[q].x += fabsf(cv.x - xq);
            acc[q].y += fabsf(cv.y - xq);
            acc[q].z += fabsf(cv.z - xq);
            acc[q].w += fabsf(cv.w - xq);
        }
    }

    // ---- logits: sum exp(-dist) per class via LDS atomics ----
    if (active) {
        int4 yv = *(const int4*)(cy + cl);
#pragma unroll
        for (int q = 0; q < QT; ++q) {
            atomicAdd(&lds_logits[q * DOUT + yv.x], __expf(-acc[q].x));
            atomicAdd(&lds_logits[q * DOUT + yv.y], __expf(-acc[q].y));
            atomicAdd(&lds_logits[q * DOUT + yv.z], __expf(-acc[q].z));
            atomicAdd(&lds_logits[q * DOUT + yv.w], __expf(-acc[q].w));
        }
    }

    const int lane = tid & 63, wave = tid >> 6;

    // ---- per-q chunk min(dist) ----
#pragma unroll
    for (int q = 0; q < QT; ++q) {
        float v = active ? fminf(fminf(acc[q].x, acc[q].y), fminf(acc[q].z, acc[q].w))
                         : INFINITY;
#pragma unroll
        for (int m = 32; m >= 1; m >>= 1) v = fminf(v, __shfl_xor(v, m));
        if (lane == 0) wred[q * 4 + wave] = v;
    }
    __syncthreads();
    if (tid < QT) {
        float m = wred[tid * 4];
#pragma unroll
        for (int w = 1; w < 4; ++w) m = fminf(m, wred[tid * 4 + w]);
        m_sh[tid] = m;
    }
    __syncthreads();

    // ---- stable sum: s = sum exp(m - dist) over the whole chunk ----
#pragma unroll
    for (int q = 0; q < QT; ++q) {
        float m = m_sh[q];
        float s = active ? (__expf(m - acc[q].x) + __expf(m - acc[q].y) +
                            __expf(m - acc[q].z) + __expf(m - acc[q].w))
                         : 0.f;
#pragma unroll
        for (int mm = 32; mm >= 1; mm >>= 1) s += __shfl_xor(s, mm);
        if (lane == 0) wred[q * 4 + wave] = s;
    }
    __syncthreads();
    if (tid < QT) {
        float s = 0.f;
#pragma unroll
        for (int w = 0; w < 4; ++w) s += wred[tid * 4 + w];
        // per-(q, chunk) partial: lse_chunk = log(s) - m
        *(float2*)(parts + 2 * ((size_t)(q0 + tid) * NCHUNK + chunk)) =
            make_float2(m_sh[tid], s);
    }
    __syncthreads();
    if (tid < QT * DOUT)
        atomicAdd(&g_logits[q0 * DOUT + tid], lds_logits[tid]);
}

// ---------- finalize ----------
__global__ void finalize(const float* __restrict__ g_logits, const float* __restrict__ parts,
                         float* __restrict__ out) {
    int q = blockIdx.x * 256 + threadIdx.x;
    if (q >= NQ) return;
    float lse = 0.f;
#pragma unroll
    for (int ch = 0; ch < NCHUNK; ++ch) {
        float2 p = *(const float2*)(parts + 2 * ((size_t)q * NCHUNK + ch));
        lse += logf(p.y) - p.x;          // log(sum exp(m-d)) - m
    }
#pragma unroll
    for (int k = 0; k < DOUT; ++k)
        out[q * DOUT + k] = logf(g_logits[q * DOUT + k] + 1e-8f) - lse;
}

extern "C" void kernel_launch(void* const* d_in, const int* in_sizes, int n_in,
                              void* d_out, int out_size, void* d_ws, size_t ws_size,
                              hipStream_t stream) {
    const float* x_num = (const float*)d_in[0];
    const float* x_cat = (const float*)d_in[1];
    const float* c_num = (const float*)d_in[2];
    const float* c_cat = (const float*)d_in[3];
    const int*   c_y   = (const int*)d_in[4];
    const float* delta = (const float*)d_in[5];
    const float* u     = (const float*)d_in[6];

    float* ws = (float*)d_ws;
    float* cEnc = ws;                             // 26*8000 = 208,000 floats
    float* qEnc = cEnc + (size_t)DENC * NC;       // 26*512  = 13,312
    float* g_logits = qEnc + (size_t)DENC * NQ;   // 5,120
    float* parts = g_logits + NQ * DOUT;          // 512*8*2 = 8,192

    const int total = (NC + NQ) * DENC + NQ * DOUT;
    encode<<<(total + 255) / 256, 256, 0, stream>>>(
        c_num, c_cat, x_num, x_cat, delta, u, cEnc, qEnc, g_logits);
    nca_main<<<dim3(NCHUNK, NQ / QT), 256, 0, stream>>>(
        cEnc, qEnc, c_y, g_logits, parts);
    finalize<<<(NQ + 255) / 256, 256, 0, stream>>>(g_logits, parts, (float*)d_out);
}